// Round 13
// baseline (2909.747 us; speedup 1.0000x reference)
//
#include <hip/hip_runtime.h>
#include <math.h>
#include <stdint.h>

// Greedy DPP MAP — persistent kernel, round 13.
// N=8192, D=512, K=256. 64 blocks x 1024 threads (16 waves, 1 block/CU).
// Same total parallelism as r9/r12 (65,536 threads, 8 lanes/row) but the
// straggler pool / sync participant count drops 256 -> 64:
//  - 64 slot lines; wave0 polls 1 line PER LANE (64x64 = 4K line-req/round
//    vs r9's 65K). Butterfly reduce -> winner, no second hop.
//  - fn_j fetched by 64 blocks (8/XCD) instead of 256.
//  - own-row dot reads cached global FN (L2-resident after first touch;
//    FN is bypass-written ONCE at init before any read -> never stale).
//    lds_fn dropped; lds_ct (128 rows) = 135KB fits in 160KB LDS.
//  - init is two-pass over F to keep VGPR <= 128 (16 waves/CU must fit).
// Keeps r12's drain-free S3 (raw s_barrier + lgkmcnt), sc0sc1 bypass writes
// for cisT/FN/slots, plain cached reads for fn_j/cisT[j], tag ping-pong.
// No fences / ordered atomics anywhere.

#define N 8192
#define D 512
#define K 256
#define LAMBDA_REG 0.01f
#define NBLK 64
#define NTHR 1024
#define ROWS 128         // rows per block
#define CS   68          // floats per 64-float chunk (64 + 4 pad) in lds_gj
#define CTS  264         // floats per row in lds_ct
#define SSTR 8           // u64s per slot line (64B)
#define SCOPE __HIP_MEMORY_SCOPE_AGENT

typedef unsigned long long u64;
typedef float f32x4 __attribute__((ext_vector_type(4)));

struct __align__(8) Pick { float v; int i; };

__device__ __forceinline__ bool better(float av, int ai, float bv, int bi) {
    // first-max semantics (jnp.argmax tie-break: lowest index wins)
    return (av > bv) || (av == bv && ai < bi);
}

__device__ __forceinline__ u64 pack_slot(float v, int idx, int tag) {
    unsigned hi = ((unsigned)tag << 13) | (unsigned)idx;   // idx < 8192
    return ((u64)hi << 32) | (u64)__float_as_uint(v);
}

__device__ __forceinline__ void bypass_store_u64(u64* p, u64 v) {
    asm volatile("global_store_dwordx2 %0, %1, off sc0 sc1"
                 :: "v"(p), "v"(v) : "memory");
}

__device__ __forceinline__ void bypass_store_f32x4(const f32x4* p, f32x4 v) {
    asm volatile("global_store_dwordx4 %0, %1, off sc0 sc1"
                 :: "v"(p), "v"(v) : "memory");
}

__global__ __launch_bounds__(NTHR, 4) void dpp_kernel(
        const float* __restrict__ F, const float* __restrict__ q,
        float* __restrict__ FN, float* __restrict__ cisT,
        u64* __restrict__ slots, int* __restrict__ out)
{
    const int tid  = threadIdx.x;
    const int blk  = blockIdx.x;
    const int wid  = tid >> 6;        // wave 0..15
    const int lane = tid & 63;
    const int r    = tid >> 3;        // local row 0..127
    const int c    = tid & 7;         // chunk lane 0..7
    const int n    = blk * ROWS + r;  // global row

    __shared__ __align__(16) float lds_ct[ROWS * CTS];  // own cis prefix (135KB)
    __shared__ __align__(16) float lds_gj[8 * CS];      // fn_j staged
    __shared__ __align__(16) float lds_cj[K];           // cisT[j][0..t)
    __shared__ Pick lds_wave[NTHR / 64];
    __shared__ Pick lds_final;

    const f32x4* F4  = reinterpret_cast<const f32x4*>(F);
    f32x4*       FN4 = reinterpret_cast<f32x4*>(FN);

    // ---- init (two-pass, low VGPR): norm, then normalize+store ----
    float dloc, qn;
    bool  masked = false;
    {
        const f32x4* src = F4 + (size_t)n * (D / 4) + c * 16;
        float ss = 0.f;
        #pragma unroll 4
        for (int i = 0; i < 16; ++i) {
            f32x4 v = src[i];
            ss = fmaf(v.x, v.x, ss); ss = fmaf(v.y, v.y, ss);
            ss = fmaf(v.z, v.z, ss); ss = fmaf(v.w, v.w, ss);
        }
        ss += __shfl_xor(ss, 1); ss += __shfl_xor(ss, 2); ss += __shfl_xor(ss, 4);
        const float norm = sqrtf(ss);
        f32x4* dst = FN4 + (size_t)n * (D / 4) + c * 16;
        float ssn = 0.f;
        #pragma unroll 4
        for (int i = 0; i < 16; ++i) {
            f32x4 v = src[i];                 // re-load (L1/L2 hit)
            v.x /= norm; v.y /= norm; v.z /= norm; v.w /= norm;
            bypass_store_f32x4(dst + i, v);
            ssn = fmaf(v.x, v.x, ssn); ssn = fmaf(v.y, v.y, ssn);
            ssn = fmaf(v.z, v.z, ssn); ssn = fmaf(v.w, v.w, ssn);
        }
        ssn += __shfl_xor(ssn, 1); ssn += __shfl_xor(ssn, 2); ssn += __shfl_xor(ssn, 4);
        qn = q[n];
        dloc = fmaf(sqrtf(qn * qn), ssn, LAMBDA_REG);
    }

    // ---- initial block partial (tag 0, buffer 0) — one-time safe drain ----
    {
        float v = dloc; int idx = n;
        #pragma unroll
        for (int m = 32; m > 0; m >>= 1) {
            float ov = __shfl_xor(v, m);
            int   oi = __shfl_xor(idx, m);
            if (better(ov, oi, v, idx)) { v = ov; idx = oi; }
        }
        if (lane == 0) { lds_wave[wid].v = v; lds_wave[wid].i = idx; }
        asm volatile("s_waitcnt vmcnt(0)" ::: "memory");  // own FN stores at MALL
        __syncthreads();
        if (tid == 0) {
            Pick p = lds_wave[0];
            #pragma unroll
            for (int w = 1; w < NTHR / 64; ++w) {
                Pick o = lds_wave[w];
                if (better(o.v, o.i, p.v, p.i)) p = o;
            }
            bypass_store_u64(&slots[blk * SSTR], pack_slot(p.v, p.i, 0));
        }
    }

    for (int t = 0; t < K; ++t) {
        const unsigned want = (unsigned)t;

        // ---- A: wave0 polls 64 slot lines, ONE per lane ----
        if (tid < 64) {
            const u64* pb = slots + (t & 1) * NBLK * SSTR;
            u64 x;
            while (true) {
                x = __hip_atomic_load(pb + tid * SSTR, __ATOMIC_RELAXED, SCOPE);
                if (__all((unsigned)(x >> 45) == want)) break;
                __builtin_amdgcn_s_sleep(1);
            }
            asm volatile("" ::: "memory");
            float v = __uint_as_float((unsigned)x);
            int idx = (int)((x >> 32) & 8191u);
            #pragma unroll
            for (int m = 32; m > 0; m >>= 1) {
                float ov = __shfl_xor(v, m);
                int   oi = __shfl_xor(idx, m);
                if (better(ov, oi, v, idx)) { v = ov; idx = oi; }
            }
            if (tid == 0) { lds_final.v = v; lds_final.i = idx; }
        }
        __syncthreads();                              // S1
        const float dj = lds_final.v;
        const int   j  = lds_final.i;

        if (blk == 0 && tid == 0) out[t] = j;
        if (t == K - 1) break;

        const float sj = sqrtf(dj);
        const float qj = q[j];

        // ---- B: stage fn_j (threads 0-127) + cisT[j][0..t) (256-511) ----
        if (tid < 128) {
            f32x4 gv = FN4[(size_t)j * (D / 4) + tid];
            *reinterpret_cast<f32x4*>(&lds_gj[(tid >> 4) * CS + (tid & 15) * 4]) = gv;
        } else if (tid >= 256 && tid < 512) {
            const int tt = tid - 256;
            if (tt < t) lds_cj[tt] = cisT[(size_t)j * K + tt];
        }
        __syncthreads();                              // S2

        // ---- C: dot = cached-global own row x LDS fn_j ----
        const f32x4* ow = FN4 + (size_t)n * (D / 4) + c * 16;  // own row (L2)
        const float* grow = &lds_gj[c * CS];
        f32x4 a = {0.f, 0.f, 0.f, 0.f};
        #pragma unroll 4
        for (int i = 0; i < 16; ++i) {
            f32x4 v = ow[i];
            f32x4 g = *reinterpret_cast<const f32x4*>(grow + 4 * i);
            a.x = fmaf(v.x, g.x, a.x); a.y = fmaf(v.y, g.y, a.y);
            a.z = fmaf(v.z, g.z, a.z); a.w = fmaf(v.w, g.w, a.w);
        }
        float dot = (a.x + a.y) + (a.z + a.w);
        dot += __shfl_xor(dot, 1); dot += __shfl_xor(dot, 2); dot += __shfl_xor(dot, 4);
        float Ljn = sqrtf(qj * qn) * dot;
        if (n == j) Ljn += LAMBDA_REG;

        float cd = 0.f;
        const float* ctrow = &lds_ct[r * CTS];
        for (int tt = c; tt < t; tt += 8)
            cd = fmaf(lds_cj[tt], ctrow[tt], cd);
        cd += __shfl_xor(cd, 1); cd += __shfl_xor(cd, 2); cd += __shfl_xor(cd, 4);

        const float e = (Ljn - cd) / sj;
        if (c == 0) {
            lds_ct[r * CTS + t] = e;
            const float* ep = cisT + (size_t)n * K + t;
            asm volatile("global_store_dword %0, %1, off sc0 sc1"
                         :: "v"(ep), "v"(e) : "memory");    // fire-and-forget
        }
        dloc = fmaf(-e, e, dloc);
        if (n == j) masked = true;

        // ---- block partial for t+1; S3 = raw barrier, NO vmcnt drain ----
        {
            float v = masked ? -INFINITY : dloc; int idx = n;
            #pragma unroll
            for (int m = 32; m > 0; m >>= 1) {
                float ov = __shfl_xor(v, m);
                int   oi = __shfl_xor(idx, m);
                if (better(ov, oi, v, idx)) { v = ov; idx = oi; }
            }
            if (lane == 0) { lds_wave[wid].v = v; lds_wave[wid].i = idx; }
        }
        asm volatile("s_waitcnt lgkmcnt(0)" ::: "memory");  // LDS writes only
        __builtin_amdgcn_sched_barrier(0);
        __builtin_amdgcn_s_barrier();                       // S3 (no vmcnt!)
        __builtin_amdgcn_sched_barrier(0);
        if (tid == 0) {
            Pick p = lds_wave[0];
            #pragma unroll
            for (int w = 1; w < NTHR / 64; ++w) {
                Pick o = lds_wave[w];
                if (better(o.v, o.i, p.v, p.i)) p = o;
            }
            bypass_store_u64(&slots[(((t + 1) & 1) * NBLK + blk) * SSTR],
                             pack_slot(p.v, p.i, t + 1));
        }
    }
}

extern "C" void kernel_launch(void* const* d_in, const int* in_sizes, int n_in,
                              void* d_out, int out_size, void* d_ws, size_t ws_size,
                              hipStream_t stream) {
    const float* F = (const float*)d_in[0];
    const float* q = (const float*)d_in[1];
    int* out = (int*)d_out;

    uint8_t* w = (uint8_t*)d_ws;
    u64*   slots = (u64*)(w + 4096);            // [2][64] 64B lines = 8 KB
    float* FN    = (float*)(w + 131072);                      // 16 MB
    float* cisT  = (float*)(w + 131072 + (size_t)N * D * 4);  // 8 MB

    // invalidate all slot tags each launch (graph replays reuse ws)
    hipMemsetAsync((void*)w, 0xFF, 65536, stream);
    hipLaunchKernelGGL(dpp_kernel, dim3(NBLK), dim3(NTHR), 0, stream,
                       F, q, FN, cisT, slots, out);
}

// Round 14
// 1622.561 us; speedup vs baseline: 1.7933x; 1.7933x over previous
//
#include <hip/hip_runtime.h>
#include <math.h>
#include <stdint.h>

// Greedy DPP MAP — persistent kernel, round 14 = round 12 base (1177us) with
// the B-phase dissolved:
//  - cisT[j][0..t) is staged into lds_cj by WAVE 0 right after detect (all
//    its lanes hold j post-butterfly), so S1 doubles as the cj-ready barrier.
//  - fn_j is read directly from cached global inside the dot (broadcast row:
//    first toucher per XCD pays MALL, rest hit L2/L1; 16 independent loads).
//    lds_gj and S2 are deleted. (NOT r13's mistake: own-row stays in LDS —
//    r13 moved 16MB/step of UNIQUE row traffic to global and died; fn_j is
//    a single shared 2KB row.)
// Per-step barriers: S1 (__syncthreads) and S3 (raw s_barrier, no vmcnt
// drain — r12-validated). Everything else identical to r12: 256x256,
// 8 lanes/row, lds_fn row cache, wave0-only poll of 256 spread 64B lines,
// sc0sc1 bypass writes, plain cached broadcast reads, tag ping-pong.

#define N 8192
#define D 512
#define K 256
#define LAMBDA_REG 0.01f
#define NBLK 256
#define NTHR 256
#define ROWS 32          // rows per block
#define RS   560         // floats per row in lds_fn
#define CS   68          // floats per 64-float chunk (64 + 4 pad)
#define CTS  264         // floats per row in lds_ct
#define SSTR 8           // u64s per slot line (64B)
#define SCOPE __HIP_MEMORY_SCOPE_AGENT

typedef unsigned long long u64;
typedef float f32x4 __attribute__((ext_vector_type(4)));

struct __align__(8) Pick { float v; int i; };

__device__ __forceinline__ bool better(float av, int ai, float bv, int bi) {
    // first-max semantics (jnp.argmax tie-break: lowest index wins)
    return (av > bv) || (av == bv && ai < bi);
}

__device__ __forceinline__ u64 pack_slot(float v, int idx, int tag) {
    unsigned hi = ((unsigned)tag << 13) | (unsigned)idx;   // idx < 8192
    return ((u64)hi << 32) | (u64)__float_as_uint(v);
}

__device__ __forceinline__ void bypass_store_u64(u64* p, u64 v) {
    asm volatile("global_store_dwordx2 %0, %1, off sc0 sc1"
                 :: "v"(p), "v"(v) : "memory");
}

__device__ __forceinline__ void bypass_store_f32x4(const f32x4* p, f32x4 v) {
    asm volatile("global_store_dwordx4 %0, %1, off sc0 sc1"
                 :: "v"(p), "v"(v) : "memory");
}

__global__ __launch_bounds__(NTHR, 1) void dpp_kernel(
        const float* __restrict__ F, const float* __restrict__ q,
        float* __restrict__ FN, float* __restrict__ cisT,
        u64* __restrict__ slots, int* __restrict__ out)
{
    const int tid = threadIdx.x;
    const int blk = blockIdx.x;
    const int r   = tid >> 3;        // local row 0..31
    const int c   = tid & 7;         // chunk lane 0..7
    const int n   = blk * ROWS + r;  // global row

    __shared__ __align__(16) float lds_fn[ROWS * RS];   // own FN rows
    __shared__ __align__(16) float lds_ct[ROWS * CTS];  // own cis prefix
    __shared__ __align__(16) float lds_cj[K];           // cisT[j][0..t)
    __shared__ Pick lds_wave[NTHR / 64];
    __shared__ Pick lds_final;

    const f32x4* F4  = reinterpret_cast<const f32x4*>(F);
    f32x4*       FN4 = reinterpret_cast<f32x4*>(FN);

    // ---- init: load own row, normalize; FN written via MALL-bypass stores ----
    float dloc, qn;
    bool  masked = false;
    {
        const f32x4* src = F4 + (size_t)n * (D / 4) + c * 16;
        float* frow = &lds_fn[r * RS + c * CS];
        float ss = 0.f;
        #pragma unroll
        for (int i = 0; i < 16; ++i) {
            f32x4 v = src[i];
            *reinterpret_cast<f32x4*>(frow + 4 * i) = v;
            ss = fmaf(v.x, v.x, ss); ss = fmaf(v.y, v.y, ss);
            ss = fmaf(v.z, v.z, ss); ss = fmaf(v.w, v.w, ss);
        }
        ss += __shfl_xor(ss, 1); ss += __shfl_xor(ss, 2); ss += __shfl_xor(ss, 4);
        const float norm = sqrtf(ss);
        f32x4* dst = FN4 + (size_t)n * (D / 4) + c * 16;
        float ssn = 0.f;
        #pragma unroll
        for (int i = 0; i < 16; ++i) {
            f32x4 v = *reinterpret_cast<f32x4*>(frow + 4 * i);
            v.x /= norm; v.y /= norm; v.z /= norm; v.w /= norm;
            *reinterpret_cast<f32x4*>(frow + 4 * i) = v;
            bypass_store_f32x4(dst + i, v);
            ssn = fmaf(v.x, v.x, ssn); ssn = fmaf(v.y, v.y, ssn);
            ssn = fmaf(v.z, v.z, ssn); ssn = fmaf(v.w, v.w, ssn);
        }
        ssn += __shfl_xor(ssn, 1); ssn += __shfl_xor(ssn, 2); ssn += __shfl_xor(ssn, 4);
        qn = q[n];
        dloc = fmaf(sqrtf(qn * qn), ssn, LAMBDA_REG);
    }

    // ---- initial block partial (tag 0, buffer 0) — one-time safe drain ----
    {
        float v = dloc; int idx = n;
        #pragma unroll
        for (int m = 32; m > 0; m >>= 1) {
            float ov = __shfl_xor(v, m);
            int   oi = __shfl_xor(idx, m);
            if (better(ov, oi, v, idx)) { v = ov; idx = oi; }
        }
        if ((tid & 63) == 0) { lds_wave[tid >> 6].v = v; lds_wave[tid >> 6].i = idx; }
        asm volatile("s_waitcnt vmcnt(0)" ::: "memory");  // own FN stores at MALL
        __syncthreads();
        if (tid == 0) {
            Pick p = lds_wave[0];
            #pragma unroll
            for (int w = 1; w < NTHR / 64; ++w) {
                Pick o = lds_wave[w];
                if (better(o.v, o.i, p.v, p.i)) p = o;
            }
            bypass_store_u64(&slots[blk * SSTR], pack_slot(p.v, p.i, 0));
        }
    }

    for (int t = 0; t < K; ++t) {
        const unsigned want = (unsigned)t;

        // ---- A: wave0 polls all 256 spread slot lines (4/lane), then
        //         stages cisT[j][0..t) itself (it alone knows j pre-S1) ----
        if (tid < 64) {
            const u64* pb = slots + (t & 1) * NBLK * SSTR;
            u64 x0, x1, x2, x3;
            while (true) {
                x0 = __hip_atomic_load(pb + (tid * 4 + 0) * SSTR, __ATOMIC_RELAXED, SCOPE);
                x1 = __hip_atomic_load(pb + (tid * 4 + 1) * SSTR, __ATOMIC_RELAXED, SCOPE);
                x2 = __hip_atomic_load(pb + (tid * 4 + 2) * SSTR, __ATOMIC_RELAXED, SCOPE);
                x3 = __hip_atomic_load(pb + (tid * 4 + 3) * SSTR, __ATOMIC_RELAXED, SCOPE);
                bool ok = ((unsigned)(x0 >> 45) == want) &&
                          ((unsigned)(x1 >> 45) == want) &&
                          ((unsigned)(x2 >> 45) == want) &&
                          ((unsigned)(x3 >> 45) == want);
                if (__all(ok)) break;
                __builtin_amdgcn_s_sleep(1);
            }
            asm volatile("" ::: "memory");
            float v = __uint_as_float((unsigned)x0);
            int idx = (int)((x0 >> 32) & 8191u);
            {
                float w = __uint_as_float((unsigned)x1); int k1 = (int)((x1 >> 32) & 8191u);
                if (better(w, k1, v, idx)) { v = w; idx = k1; }
                w = __uint_as_float((unsigned)x2); k1 = (int)((x2 >> 32) & 8191u);
                if (better(w, k1, v, idx)) { v = w; idx = k1; }
                w = __uint_as_float((unsigned)x3); k1 = (int)((x3 >> 32) & 8191u);
                if (better(w, k1, v, idx)) { v = w; idx = k1; }
            }
            #pragma unroll
            for (int m = 32; m > 0; m >>= 1) {   // butterfly: all 64 lanes converge
                float ov = __shfl_xor(v, m);
                int   oi = __shfl_xor(idx, m);
                if (better(ov, oi, v, idx)) { v = ov; idx = oi; }
            }
            if (tid == 0) { lds_final.v = v; lds_final.i = idx; }
            // stage cj prefix now (j == idx in every lane)
            if (t < K - 1) {
                const float* cjrow = cisT + (size_t)idx * K;
                for (int tt = tid; tt < t; tt += 64)
                    lds_cj[tt] = cjrow[tt];
            }
        }
        __syncthreads();                              // S1 (winner + cj ready)
        const float dj = lds_final.v;
        const int   j  = lds_final.i;

        if (blk == 0 && tid == 0) out[t] = j;
        if (t == K - 1) break;

        const float sj = sqrtf(dj);
        const float qj = q[j];

        // ---- C: dot = LDS own row x cached-global fn_j (broadcast row) ----
        const float* frow = &lds_fn[r * RS + c * CS];
        const f32x4* gj   = FN4 + (size_t)j * (D / 4) + c * 16;
        f32x4 a = {0.f, 0.f, 0.f, 0.f};
        #pragma unroll
        for (int i = 0; i < 16; ++i) {
            f32x4 v = *reinterpret_cast<const f32x4*>(frow + 4 * i);
            f32x4 g = gj[i];
            a.x = fmaf(v.x, g.x, a.x); a.y = fmaf(v.y, g.y, a.y);
            a.z = fmaf(v.z, g.z, a.z); a.w = fmaf(v.w, g.w, a.w);
        }
        float dot = (a.x + a.y) + (a.z + a.w);
        dot += __shfl_xor(dot, 1); dot += __shfl_xor(dot, 2); dot += __shfl_xor(dot, 4);
        float Ljn = sqrtf(qj * qn) * dot;
        if (n == j) Ljn += LAMBDA_REG;

        float cd = 0.f;
        const float* ctrow = &lds_ct[r * CTS];
        for (int tt = c; tt < t; tt += 8)
            cd = fmaf(lds_cj[tt], ctrow[tt], cd);
        cd += __shfl_xor(cd, 1); cd += __shfl_xor(cd, 2); cd += __shfl_xor(cd, 4);

        const float e = (Ljn - cd) / sj;
        if (c == 0) {
            lds_ct[r * CTS + t] = e;
            const float* ep = cisT + (size_t)n * K + t;
            asm volatile("global_store_dword %0, %1, off sc0 sc1"
                         :: "v"(ep), "v"(e) : "memory");    // fire-and-forget
        }
        dloc = fmaf(-e, e, dloc);
        if (n == j) masked = true;

        // ---- block partial for t+1; S3 = raw barrier, NO vmcnt drain ----
        {
            float v = masked ? -INFINITY : dloc; int idx = n;
            #pragma unroll
            for (int m = 32; m > 0; m >>= 1) {
                float ov = __shfl_xor(v, m);
                int   oi = __shfl_xor(idx, m);
                if (better(ov, oi, v, idx)) { v = ov; idx = oi; }
            }
            if ((tid & 63) == 0) { lds_wave[tid >> 6].v = v; lds_wave[tid >> 6].i = idx; }
        }
        asm volatile("s_waitcnt lgkmcnt(0)" ::: "memory");  // LDS writes only
        __builtin_amdgcn_sched_barrier(0);
        __builtin_amdgcn_s_barrier();                       // S3 (no vmcnt!)
        __builtin_amdgcn_sched_barrier(0);
        if (tid == 0) {
            Pick p = lds_wave[0];
            #pragma unroll
            for (int w = 1; w < NTHR / 64; ++w) {
                Pick o = lds_wave[w];
                if (better(o.v, o.i, p.v, p.i)) p = o;
            }
            bypass_store_u64(&slots[(((t + 1) & 1) * NBLK + blk) * SSTR],
                             pack_slot(p.v, p.i, t + 1));
        }
    }
}

extern "C" void kernel_launch(void* const* d_in, const int* in_sizes, int n_in,
                              void* d_out, int out_size, void* d_ws, size_t ws_size,
                              hipStream_t stream) {
    const float* F = (const float*)d_in[0];
    const float* q = (const float*)d_in[1];
    int* out = (int*)d_out;

    uint8_t* w = (uint8_t*)d_ws;
    u64*   slots = (u64*)(w + 4096);            // [2][256] 64B lines = 32 KB
    float* FN    = (float*)(w + 131072);                      // 16 MB
    float* cisT  = (float*)(w + 131072 + (size_t)N * D * 4);  // 8 MB

    // invalidate all slot tags each launch (graph replays reuse ws)
    hipMemsetAsync((void*)w, 0xFF, 65536, stream);
    hipLaunchKernelGGL(dpp_kernel, dim3(NBLK), dim3(NTHR), 0, stream,
                       F, q, FN, cisT, slots, out);
}

// Round 15
// 1182.523 us; speedup vs baseline: 2.4606x; 1.3721x over previous
//
#include <hip/hip_runtime.h>
#include <math.h>
#include <stdint.h>

// Greedy DPP MAP — persistent kernel, round 15 = FINAL = round 12 (best,
// 1177-1182us). Reverts r13/r14 experiments (both regressed: moving the
// own-row or fn_j operand out of LDS turns the C-phase into a MALL-latency
// chain; 64-block variant can't fit own rows in LDS).
//
// Structure: 256 blocks x 256 threads (1 block/CU), 8 lanes/row.
//  - own FN rows + own cis prefix in LDS (conflict-engineered strides).
//  - zero fences / ordered atomics: all cross-block bytes (FN, cisT, slots)
//    move via sc0+sc1 bypass ops at the MALL; FN/cisT consumed via plain
//    cached loads (write-once-before-first-read, read-once-ever => fresh).
//  - exchange: each block publishes one epoch-tagged 8B partial to its own
//    64B slot line; wave0 of every block polls all 256 lines (4/lane),
//    butterfly-reduces; ping-pong buffers; lowest-index tie-break == jnp.
//  - S3 is a raw s_barrier (lgkmcnt only, no vmcnt drain) — e-store acks
//    absorb during the next poll window (r10/r12-validated).
// Per-step cost 4.6us = latency floor of the max-over-256-blocks exchange;
// HBM 1.5%, VALU 10%, MfmaUtil 0 — not memory/compute bound.

#define N 8192
#define D 512
#define K 256
#define LAMBDA_REG 0.01f
#define NBLK 256
#define NTHR 256
#define ROWS 32          // rows per block
#define RS   560         // floats per row in lds_fn
#define CS   68          // floats per 64-float chunk (64 + 4 pad)
#define CTS  264         // floats per row in lds_ct
#define SSTR 8           // u64s per slot line (64B)
#define SCOPE __HIP_MEMORY_SCOPE_AGENT

typedef unsigned long long u64;
typedef float f32x4 __attribute__((ext_vector_type(4)));

struct __align__(8) Pick { float v; int i; };

__device__ __forceinline__ bool better(float av, int ai, float bv, int bi) {
    // first-max semantics (jnp.argmax tie-break: lowest index wins)
    return (av > bv) || (av == bv && ai < bi);
}

__device__ __forceinline__ u64 pack_slot(float v, int idx, int tag) {
    unsigned hi = ((unsigned)tag << 13) | (unsigned)idx;   // idx < 8192
    return ((u64)hi << 32) | (u64)__float_as_uint(v);
}

__device__ __forceinline__ void bypass_store_u64(u64* p, u64 v) {
    asm volatile("global_store_dwordx2 %0, %1, off sc0 sc1"
                 :: "v"(p), "v"(v) : "memory");
}

__device__ __forceinline__ void bypass_store_f32x4(const f32x4* p, f32x4 v) {
    asm volatile("global_store_dwordx4 %0, %1, off sc0 sc1"
                 :: "v"(p), "v"(v) : "memory");
}

__global__ __launch_bounds__(NTHR, 1) void dpp_kernel(
        const float* __restrict__ F, const float* __restrict__ q,
        float* __restrict__ FN, float* __restrict__ cisT,
        u64* __restrict__ slots, int* __restrict__ out)
{
    const int tid = threadIdx.x;
    const int blk = blockIdx.x;
    const int r   = tid >> 3;        // local row 0..31
    const int c   = tid & 7;         // chunk lane 0..7
    const int n   = blk * ROWS + r;  // global row

    __shared__ __align__(16) float lds_fn[ROWS * RS];   // own FN rows
    __shared__ __align__(16) float lds_ct[ROWS * CTS];  // own cis prefix
    __shared__ __align__(16) float lds_gj[8 * CS];      // fn_j staged
    __shared__ __align__(16) float lds_cj[K];           // cisT[j][0..t)
    __shared__ Pick lds_wave[NTHR / 64];
    __shared__ Pick lds_final;

    const f32x4* F4  = reinterpret_cast<const f32x4*>(F);
    f32x4*       FN4 = reinterpret_cast<f32x4*>(FN);

    // ---- init: load own row, normalize; FN written via MALL-bypass stores ----
    float dloc, qn;
    bool  masked = false;
    {
        const f32x4* src = F4 + (size_t)n * (D / 4) + c * 16;
        float* frow = &lds_fn[r * RS + c * CS];
        float ss = 0.f;
        #pragma unroll
        for (int i = 0; i < 16; ++i) {
            f32x4 v = src[i];
            *reinterpret_cast<f32x4*>(frow + 4 * i) = v;
            ss = fmaf(v.x, v.x, ss); ss = fmaf(v.y, v.y, ss);
            ss = fmaf(v.z, v.z, ss); ss = fmaf(v.w, v.w, ss);
        }
        ss += __shfl_xor(ss, 1); ss += __shfl_xor(ss, 2); ss += __shfl_xor(ss, 4);
        const float norm = sqrtf(ss);
        f32x4* dst = FN4 + (size_t)n * (D / 4) + c * 16;
        float ssn = 0.f;
        #pragma unroll
        for (int i = 0; i < 16; ++i) {
            f32x4 v = *reinterpret_cast<f32x4*>(frow + 4 * i);
            v.x /= norm; v.y /= norm; v.z /= norm; v.w /= norm;
            *reinterpret_cast<f32x4*>(frow + 4 * i) = v;
            bypass_store_f32x4(dst + i, v);
            ssn = fmaf(v.x, v.x, ssn); ssn = fmaf(v.y, v.y, ssn);
            ssn = fmaf(v.z, v.z, ssn); ssn = fmaf(v.w, v.w, ssn);
        }
        ssn += __shfl_xor(ssn, 1); ssn += __shfl_xor(ssn, 2); ssn += __shfl_xor(ssn, 4);
        qn = q[n];
        dloc = fmaf(sqrtf(qn * qn), ssn, LAMBDA_REG);
    }

    // ---- initial block partial (tag 0, buffer 0) — one-time safe drain ----
    {
        float v = dloc; int idx = n;
        #pragma unroll
        for (int m = 32; m > 0; m >>= 1) {
            float ov = __shfl_xor(v, m);
            int   oi = __shfl_xor(idx, m);
            if (better(ov, oi, v, idx)) { v = ov; idx = oi; }
        }
        if ((tid & 63) == 0) { lds_wave[tid >> 6].v = v; lds_wave[tid >> 6].i = idx; }
        asm volatile("s_waitcnt vmcnt(0)" ::: "memory");  // own FN stores at MALL
        __syncthreads();
        if (tid == 0) {
            Pick p = lds_wave[0];
            #pragma unroll
            for (int w = 1; w < NTHR / 64; ++w) {
                Pick o = lds_wave[w];
                if (better(o.v, o.i, p.v, p.i)) p = o;
            }
            bypass_store_u64(&slots[blk * SSTR], pack_slot(p.v, p.i, 0));
        }
    }

    for (int t = 0; t < K; ++t) {
        const unsigned want = (unsigned)t;

        // ---- A: wave0 polls all 256 spread slot lines (4/lane) ----
        if (tid < 64) {
            const u64* pb = slots + (t & 1) * NBLK * SSTR;
            u64 x0, x1, x2, x3;
            while (true) {
                x0 = __hip_atomic_load(pb + (tid * 4 + 0) * SSTR, __ATOMIC_RELAXED, SCOPE);
                x1 = __hip_atomic_load(pb + (tid * 4 + 1) * SSTR, __ATOMIC_RELAXED, SCOPE);
                x2 = __hip_atomic_load(pb + (tid * 4 + 2) * SSTR, __ATOMIC_RELAXED, SCOPE);
                x3 = __hip_atomic_load(pb + (tid * 4 + 3) * SSTR, __ATOMIC_RELAXED, SCOPE);
                bool ok = ((unsigned)(x0 >> 45) == want) &&
                          ((unsigned)(x1 >> 45) == want) &&
                          ((unsigned)(x2 >> 45) == want) &&
                          ((unsigned)(x3 >> 45) == want);
                if (__all(ok)) break;
                __builtin_amdgcn_s_sleep(1);
            }
            asm volatile("" ::: "memory");
            float v = __uint_as_float((unsigned)x0);
            int idx = (int)((x0 >> 32) & 8191u);
            {
                float w = __uint_as_float((unsigned)x1); int k1 = (int)((x1 >> 32) & 8191u);
                if (better(w, k1, v, idx)) { v = w; idx = k1; }
                w = __uint_as_float((unsigned)x2); k1 = (int)((x2 >> 32) & 8191u);
                if (better(w, k1, v, idx)) { v = w; idx = k1; }
                w = __uint_as_float((unsigned)x3); k1 = (int)((x3 >> 32) & 8191u);
                if (better(w, k1, v, idx)) { v = w; idx = k1; }
            }
            #pragma unroll
            for (int m = 32; m > 0; m >>= 1) {
                float ov = __shfl_xor(v, m);
                int   oi = __shfl_xor(idx, m);
                if (better(ov, oi, v, idx)) { v = ov; idx = oi; }
            }
            if (tid == 0) { lds_final.v = v; lds_final.i = idx; }
        }
        __syncthreads();                              // S1
        const float dj = lds_final.v;
        const int   j  = lds_final.i;

        if (blk == 0 && tid == 0) out[t] = j;
        if (t == K - 1) break;

        const float sj = sqrtf(dj);
        const float qj = q[j];

        // ---- B: parallel staging — waves 0-1: fn_j; waves 2-3: cisT[j] ----
        f32x4 gv;
        float cv0, cv1;
        int   tt0 = tid - 128, tt1 = tid;
        if (tid < 128) {
            gv = FN4[(size_t)j * (D / 4) + tid];
        } else {
            if (tt0 < t) cv0 = cisT[(size_t)j * K + tt0];
            if (tt1 < t) cv1 = cisT[(size_t)j * K + tt1];
        }
        if (tid < 128) {
            *reinterpret_cast<f32x4*>(&lds_gj[(tid >> 4) * CS + (tid & 15) * 4]) = gv;
        } else {
            if (tt0 < t) lds_cj[tt0] = cv0;
            if (tt1 < t) lds_cj[tt1] = cv1;
        }
        __syncthreads();                              // S2

        // ---- C: dot (LDS x LDS), cd, e, updates ----
        const float* frow = &lds_fn[r * RS + c * CS];
        const float* grow = &lds_gj[c * CS];
        f32x4 a = {0.f, 0.f, 0.f, 0.f};
        #pragma unroll
        for (int i = 0; i < 16; ++i) {
            f32x4 v = *reinterpret_cast<const f32x4*>(frow + 4 * i);
            f32x4 g = *reinterpret_cast<const f32x4*>(grow + 4 * i);
            a.x = fmaf(v.x, g.x, a.x); a.y = fmaf(v.y, g.y, a.y);
            a.z = fmaf(v.z, g.z, a.z); a.w = fmaf(v.w, g.w, a.w);
        }
        float dot = (a.x + a.y) + (a.z + a.w);
        dot += __shfl_xor(dot, 1); dot += __shfl_xor(dot, 2); dot += __shfl_xor(dot, 4);
        float Ljn = sqrtf(qj * qn) * dot;
        if (n == j) Ljn += LAMBDA_REG;

        float cd = 0.f;
        const float* ctrow = &lds_ct[r * CTS];
        for (int tt = c; tt < t; tt += 8)
            cd = fmaf(lds_cj[tt], ctrow[tt], cd);
        cd += __shfl_xor(cd, 1); cd += __shfl_xor(cd, 2); cd += __shfl_xor(cd, 4);

        const float e = (Ljn - cd) / sj;
        if (c == 0) {
            lds_ct[r * CTS + t] = e;
            const float* ep = cisT + (size_t)n * K + t;
            asm volatile("global_store_dword %0, %1, off sc0 sc1"
                         :: "v"(ep), "v"(e) : "memory");    // fire-and-forget
        }
        dloc = fmaf(-e, e, dloc);
        if (n == j) masked = true;

        // ---- block partial for t+1; S3 = raw barrier, NO vmcnt drain ----
        {
            float v = masked ? -INFINITY : dloc; int idx = n;
            #pragma unroll
            for (int m = 32; m > 0; m >>= 1) {
                float ov = __shfl_xor(v, m);
                int   oi = __shfl_xor(idx, m);
                if (better(ov, oi, v, idx)) { v = ov; idx = oi; }
            }
            if ((tid & 63) == 0) { lds_wave[tid >> 6].v = v; lds_wave[tid >> 6].i = idx; }
        }
        asm volatile("s_waitcnt lgkmcnt(0)" ::: "memory");  // LDS writes only
        __builtin_amdgcn_sched_barrier(0);
        __builtin_amdgcn_s_barrier();                       // S3 (no vmcnt!)
        __builtin_amdgcn_sched_barrier(0);
        if (tid == 0) {
            Pick p = lds_wave[0];
            #pragma unroll
            for (int w = 1; w < NTHR / 64; ++w) {
                Pick o = lds_wave[w];
                if (better(o.v, o.i, p.v, p.i)) p = o;
            }
            bypass_store_u64(&slots[(((t + 1) & 1) * NBLK + blk) * SSTR],
                             pack_slot(p.v, p.i, t + 1));
        }
    }
}

extern "C" void kernel_launch(void* const* d_in, const int* in_sizes, int n_in,
                              void* d_out, int out_size, void* d_ws, size_t ws_size,
                              hipStream_t stream) {
    const float* F = (const float*)d_in[0];
    const float* q = (const float*)d_in[1];
    int* out = (int*)d_out;

    uint8_t* w = (uint8_t*)d_ws;
    u64*   slots = (u64*)(w + 4096);            // [2][256] 64B lines = 32 KB
    float* FN    = (float*)(w + 131072);                      // 16 MB
    float* cisT  = (float*)(w + 131072 + (size_t)N * D * 4);  // 8 MB

    // invalidate all slot tags each launch (graph replays reuse ws)
    hipMemsetAsync((void*)w, 0xFF, 65536, stream);
    hipLaunchKernelGGL(dpp_kernel, dim3(NBLK), dim3(NTHR), 0, stream,
                       F, q, FN, cisT, slots, out);
}